// Round 1
// baseline (1529.999 us; speedup 1.0000x reference)
//
#include <hip/hip_runtime.h>
#include <hip/hip_bf16.h>
#include <math.h>

#define N_NODES 100000
#define N_EDGES 1600000
#define IN_CH 128
#define OUT_CH 128
#define EDGE_DIM 6
#define STATE_DIM 5
#define XS_DIM (IN_CH + STATE_DIM)   // 133
#define XS_STRIDE 136                // padded row stride in LDS (16B aligned rows)

// ---------------------------------------------------------------------------
// Kernel 1: per-node GEMMs.
//   Y[n][c]   = sum_k xs[n][k] * W_neg[k][c] + b_neg[c]      (k < 133)  -> ws
//   out[n][c] = elu( sum_k xs[n][k] * W_root[k][c] + b_root[c] )        -> d_out
// xs[n] = concat(x[n] (128), global_state[n] (5))
// Block: 256 threads, 16 nodes. Thread (col = tid&127, half = tid>>7) does
// 8 nodes x 2 matrices. xs staged in LDS, consumed as float4 along k.
// ---------------------------------------------------------------------------
__global__ __launch_bounds__(256) void node_gemm(
    const float* __restrict__ x, const float* __restrict__ gs,
    const float* __restrict__ Wneg, const float* __restrict__ bneg,
    const float* __restrict__ Wroot, const float* __restrict__ broot,
    float* __restrict__ Y, float* __restrict__ out)
{
    __shared__ float xs_s[16 * XS_STRIDE];
    const int tid = threadIdx.x;
    const int n0  = blockIdx.x * 16;
    const int col  = tid & 127;
    const int half = tid >> 7;   // 0 or 1

    // stage x part: 256 threads cover 2 rows per iteration
    for (int i = 0; i < 8; ++i) {
        int t = 2 * i + half;
        xs_s[t * XS_STRIDE + col] = x[(long)(n0 + t) * IN_CH + col];
    }
    // stage global_state part (5 floats per row)
    if (tid < 16 * STATE_DIM) {
        int t = tid / STATE_DIM, j = tid % STATE_DIM;
        xs_s[t * XS_STRIDE + IN_CH + j] = gs[(long)(n0 + t) * STATE_DIM + j];
    }
    __syncthreads();

    float accN[8], accR[8];
#pragma unroll
    for (int t = 0; t < 8; ++t) { accN[t] = 0.f; accR[t] = 0.f; }

    const int rowbase = half * 8;
    // k = 0..131 in steps of 4
    for (int k = 0; k < 132; k += 4) {
        float wn0 = Wneg[(k + 0) * 128 + col];
        float wn1 = Wneg[(k + 1) * 128 + col];
        float wn2 = Wneg[(k + 2) * 128 + col];
        float wn3 = Wneg[(k + 3) * 128 + col];
        float wr0 = Wroot[(k + 0) * 128 + col];
        float wr1 = Wroot[(k + 1) * 128 + col];
        float wr2 = Wroot[(k + 2) * 128 + col];
        float wr3 = Wroot[(k + 3) * 128 + col];
#pragma unroll
        for (int t = 0; t < 8; ++t) {
            const float4 v = *(const float4*)&xs_s[(rowbase + t) * XS_STRIDE + k];
            accN[t] = fmaf(v.x, wn0, accN[t]);
            accN[t] = fmaf(v.y, wn1, accN[t]);
            accN[t] = fmaf(v.z, wn2, accN[t]);
            accN[t] = fmaf(v.w, wn3, accN[t]);
            accR[t] = fmaf(v.x, wr0, accR[t]);
            accR[t] = fmaf(v.y, wr1, accR[t]);
            accR[t] = fmaf(v.z, wr2, accR[t]);
            accR[t] = fmaf(v.w, wr3, accR[t]);
        }
    }
    // k = 132 (remainder)
    {
        float wn = Wneg[132 * 128 + col];
        float wr = Wroot[132 * 128 + col];
#pragma unroll
        for (int t = 0; t < 8; ++t) {
            float v = xs_s[(rowbase + t) * XS_STRIDE + 132];
            accN[t] = fmaf(v, wn, accN[t]);
            accR[t] = fmaf(v, wr, accR[t]);
        }
    }

    const float bn = bneg[col];
    const float br = broot[col];
#pragma unroll
    for (int t = 0; t < 8; ++t) {
        int n = n0 + rowbase + t;
        Y[(long)n * 128 + col] = accN[t] + bn;     // b_neg folded into Y
        float r = accR[t] + br;
        out[(long)n * 128 + col] = (r > 0.f) ? r : (expf(r) - 1.f);
    }
}

// ---------------------------------------------------------------------------
// Kernel 2: per-edge: z = elu(Y[src] + ea @ Wneg_bottom), atomicAdd into
// out[dst]. One wave per 8 edges; lane owns cols (2*lane, 2*lane+1).
// ---------------------------------------------------------------------------
#define EDGES_PER_WAVE 8
__global__ __launch_bounds__(256) void edge_scatter(
    const int* __restrict__ idx,       // [2, E]: row0=dst(segment), row1=src
    const float* __restrict__ ea,      // [E, 6]
    const float* __restrict__ Wneg,    // [139, 128]; bottom 6 rows at 133*128
    const float* __restrict__ Y,       // [N, 128], includes b_neg
    float* __restrict__ out)           // [N, 128], pre-filled with root term
{
    const int gid  = blockIdx.x * blockDim.x + threadIdx.x;
    const int wave = gid >> 6;
    const int lane = threadIdx.x & 63;

    // bottom-6 weight columns for this lane's 2 output cols (float2)
    const float2* wb2 = (const float2*)(Wneg + 133 * 128);
    float2 wb[EDGE_DIM];
#pragma unroll
    for (int j = 0; j < EDGE_DIM; ++j) wb[j] = wb2[j * 64 + lane];

    const int e0 = wave * EDGES_PER_WAVE;
#pragma unroll 1
    for (int e = e0; e < e0 + EDGES_PER_WAVE; ++e) {
        int dst = idx[e];
        int src = idx[N_EDGES + e];
        float2 y = ((const float2*)(Y + (long)src * 128))[lane];
        float tx = y.x, ty = y.y;
#pragma unroll
        for (int j = 0; j < EDGE_DIM; ++j) {
            float a = ea[(long)e * EDGE_DIM + j];
            tx = fmaf(a, wb[j].x, tx);
            ty = fmaf(a, wb[j].y, ty);
        }
        tx = (tx > 0.f) ? tx : (expf(tx) - 1.f);
        ty = (ty > 0.f) ? ty : (expf(ty) - 1.f);
        float* o = out + (long)dst * 128 + 2 * lane;
        atomicAdd(o,     tx);
        atomicAdd(o + 1, ty);
    }
}

extern "C" void kernel_launch(void* const* d_in, const int* in_sizes, int n_in,
                              void* d_out, int out_size, void* d_ws, size_t ws_size,
                              hipStream_t stream) {
    const float* x     = (const float*)d_in[0];
    const int*   idx   = (const int*)  d_in[1];
    const float* ea    = (const float*)d_in[2];
    const float* gs    = (const float*)d_in[3];
    const float* Wneg  = (const float*)d_in[4];
    const float* bneg  = (const float*)d_in[5];
    const float* Wroot = (const float*)d_in[6];
    const float* broot = (const float*)d_in[7];
    float* out = (float*)d_out;
    float* Y   = (float*)d_ws;   // N_NODES * 128 floats = 51.2 MB

    // Kernel 1: root term -> out, Y -> ws. Must complete before edge atomics
    // (plain stores to out would race with atomicAdds) — same stream => ordered.
    node_gemm<<<N_NODES / 16, 256, 0, stream>>>(x, gs, Wneg, bneg, Wroot, broot, Y, out);

    // Kernel 2: edge MLP + scatter-add.
    const int waves  = N_EDGES / EDGES_PER_WAVE;    // 200000
    const int blocks = waves / 4;                   // 4 waves per 256-thread block
    edge_scatter<<<blocks, 256, 0, stream>>>(idx, ea, Wneg, Y, out);
}

// Round 2
// 708.393 us; speedup vs baseline: 2.1598x; 2.1598x over previous
//
#include <hip/hip_runtime.h>
#include <hip/hip_bf16.h>
#include <math.h>

#define N_NODES 100000
#define N_EDGES 1600000
#define IN_CH 128
#define OUT_CH 128
#define EDGE_DIM 6
#define STATE_DIM 5
#define XS_DIM (IN_CH + STATE_DIM)   // 133
#define XS_STRIDE 136                // padded row stride in LDS

// ---------------------------------------------------------------------------
// Kernel 1: per-node GEMMs (unchanged from R1).
//   Y[n][c]   = xs[n] @ W_neg[0:133] + b_neg      -> ws   (b_neg folded in)
//   out[n][c] = elu( xs[n] @ W_root + b_root )    -> d_out
// ---------------------------------------------------------------------------
__global__ __launch_bounds__(256) void node_gemm(
    const float* __restrict__ x, const float* __restrict__ gs,
    const float* __restrict__ Wneg, const float* __restrict__ bneg,
    const float* __restrict__ Wroot, const float* __restrict__ broot,
    float* __restrict__ Y, float* __restrict__ out)
{
    __shared__ float xs_s[16 * XS_STRIDE];
    const int tid = threadIdx.x;
    const int n0  = blockIdx.x * 16;
    const int col  = tid & 127;
    const int half = tid >> 7;

    for (int i = 0; i < 8; ++i) {
        int t = 2 * i + half;
        xs_s[t * XS_STRIDE + col] = x[(long)(n0 + t) * IN_CH + col];
    }
    if (tid < 16 * STATE_DIM) {
        int t = tid / STATE_DIM, j = tid % STATE_DIM;
        xs_s[t * XS_STRIDE + IN_CH + j] = gs[(long)(n0 + t) * STATE_DIM + j];
    }
    __syncthreads();

    float accN[8], accR[8];
#pragma unroll
    for (int t = 0; t < 8; ++t) { accN[t] = 0.f; accR[t] = 0.f; }

    const int rowbase = half * 8;
    for (int k = 0; k < 132; k += 4) {
        float wn0 = Wneg[(k + 0) * 128 + col];
        float wn1 = Wneg[(k + 1) * 128 + col];
        float wn2 = Wneg[(k + 2) * 128 + col];
        float wn3 = Wneg[(k + 3) * 128 + col];
        float wr0 = Wroot[(k + 0) * 128 + col];
        float wr1 = Wroot[(k + 1) * 128 + col];
        float wr2 = Wroot[(k + 2) * 128 + col];
        float wr3 = Wroot[(k + 3) * 128 + col];
#pragma unroll
        for (int t = 0; t < 8; ++t) {
            const float4 v = *(const float4*)&xs_s[(rowbase + t) * XS_STRIDE + k];
            accN[t] = fmaf(v.x, wn0, accN[t]);
            accN[t] = fmaf(v.y, wn1, accN[t]);
            accN[t] = fmaf(v.z, wn2, accN[t]);
            accN[t] = fmaf(v.w, wn3, accN[t]);
            accR[t] = fmaf(v.x, wr0, accR[t]);
            accR[t] = fmaf(v.y, wr1, accR[t]);
            accR[t] = fmaf(v.z, wr2, accR[t]);
            accR[t] = fmaf(v.w, wr3, accR[t]);
        }
    }
    {
        float wn = Wneg[132 * 128 + col];
        float wr = Wroot[132 * 128 + col];
#pragma unroll
        for (int t = 0; t < 8; ++t) {
            float v = xs_s[(rowbase + t) * XS_STRIDE + 132];
            accN[t] = fmaf(v, wn, accN[t]);
            accR[t] = fmaf(v, wr, accR[t]);
        }
    }

    const float bn = bneg[col];
    const float br = broot[col];
#pragma unroll
    for (int t = 0; t < 8; ++t) {
        int n = n0 + rowbase + t;
        Y[(long)n * 128 + col] = accN[t] + bn;
        float r = accR[t] + br;
        out[(long)n * 128 + col] = (r > 0.f) ? r : (expf(r) - 1.f);
    }
}

// ---------------------------------------------------------------------------
// CSR build: zero counts -> histogram over dst -> exclusive scan -> scatter
// ---------------------------------------------------------------------------
__global__ __launch_bounds__(256) void zero_counts(int* __restrict__ cnt) {
    int i = blockIdx.x * 256 + threadIdx.x;
    if (i < N_NODES) cnt[i] = 0;
}

__global__ __launch_bounds__(256) void histogram(const int* __restrict__ idx,
                                                 int* __restrict__ cnt) {
    int e = blockIdx.x * 256 + threadIdx.x;
    if (e < N_EDGES) atomicAdd(&cnt[idx[e]], 1);   // idx row 0 = dst/segment
}

// Single-block hierarchical scan: 1024 threads x 4 items = 4096/chunk.
__global__ __launch_bounds__(1024) void scan_counts(const int* __restrict__ cnt,
                                                    int* __restrict__ off,
                                                    int* __restrict__ cursor) {
    __shared__ int wsum[16];
    const int tid  = threadIdx.x;
    const int lane = tid & 63;
    const int wid  = tid >> 6;
    int carry = 0;
    for (int c0 = 0; c0 < N_NODES; c0 += 4096) {
        int i0 = c0 + tid * 4;
        int v[4], s = 0;
#pragma unroll
        for (int j = 0; j < 4; ++j) {
            v[j] = (i0 + j < N_NODES) ? cnt[i0 + j] : 0;
            s += v[j];
        }
        // inclusive wave scan of per-thread sums
        int x = s;
#pragma unroll
        for (int d = 1; d < 64; d <<= 1) {
            int t = __shfl_up(x, d);
            if (lane >= d) x += t;
        }
        if (lane == 63) wsum[wid] = x;
        __syncthreads();
        if (wid == 0 && lane < 16) {
            int w = wsum[lane];
#pragma unroll
            for (int d = 1; d < 16; d <<= 1) {
                int t = __shfl_up(w, d);
                if (lane >= d) w += t;
            }
            wsum[lane] = w;   // inclusive across waves
        }
        __syncthreads();
        int wprefix = (wid > 0) ? wsum[wid - 1] : 0;
        int total   = wsum[15];
        int excl = carry + wprefix + (x - s);
#pragma unroll
        for (int j = 0; j < 4; ++j) {
            if (i0 + j < N_NODES) { off[i0 + j] = excl; cursor[i0 + j] = excl; }
            excl += v[j];
        }
        carry += total;
        __syncthreads();   // protect wsum before next chunk
    }
}

__global__ __launch_bounds__(256) void scatter_edges(const int* __restrict__ idx,
                                                     int* __restrict__ cursor,
                                                     int* __restrict__ eids) {
    int e = blockIdx.x * 256 + threadIdx.x;
    if (e < N_EDGES) {
        int pos = atomicAdd(&cursor[idx[e]], 1);
        eids[pos] = e;
    }
}

// ---------------------------------------------------------------------------
// Aggregate: one wave per dst node. Prefetch up to 64 (eid, src, ea-row)
// one-per-lane, then loop edges: broadcast via shfl, gather Y[src] row
// (coalesced 512B), + ea@W_bottom, ELU, register-accumulate. Write out once.
// ---------------------------------------------------------------------------
__global__ __launch_bounds__(256) void aggregate(
    const int* __restrict__ idx,     // row1 (src) at idx + N_EDGES
    const float* __restrict__ ea,
    const float* __restrict__ Wneg,  // bottom 6 rows at 133*128
    const float* __restrict__ Y,
    const int* __restrict__ off, const int* __restrict__ cnt,
    const int* __restrict__ eids,
    float* __restrict__ out)
{
    const int lane = threadIdx.x & 63;
    const int n    = blockIdx.x * 4 + (threadIdx.x >> 6);
    if (n >= N_NODES) return;

    const float2* wb2 = (const float2*)(Wneg + 133 * 128);
    float2 wb[EDGE_DIM];
#pragma unroll
    for (int j = 0; j < EDGE_DIM; ++j) wb[j] = wb2[j * 64 + lane];

    const int start = off[n];
    const int deg   = cnt[n];
    float accx = 0.f, accy = 0.f;

    for (int base = 0; base < deg; base += 64) {
        const int m = min(64, deg - base);
        int src = 0;
        float ea6[EDGE_DIM];
#pragma unroll
        for (int j = 0; j < EDGE_DIM; ++j) ea6[j] = 0.f;
        if (lane < m) {
            int eid = eids[start + base + lane];
            src = idx[N_EDGES + eid];
            const float* er = ea + (long)eid * EDGE_DIM;
#pragma unroll
            for (int j = 0; j < EDGE_DIM; ++j) ea6[j] = er[j];
        }
#pragma unroll 4
        for (int e = 0; e < m; ++e) {
            int s = __shfl(src, e);
            float2 y = ((const float2*)(Y + (long)s * 128))[lane];
            float tx = y.x, ty = y.y;
#pragma unroll
            for (int j = 0; j < EDGE_DIM; ++j) {
                float a = __shfl(ea6[j], e);
                tx = fmaf(a, wb[j].x, tx);
                ty = fmaf(a, wb[j].y, ty);
            }
            tx = (tx > 0.f) ? tx : (expf(tx) - 1.f);
            ty = (ty > 0.f) ? ty : (expf(ty) - 1.f);
            accx += tx;
            accy += ty;
        }
    }

    float2* orow = (float2*)(out + (long)n * 128);
    float2 o = orow[lane];          // root term from node_gemm
    o.x += accx;
    o.y += accy;
    orow[lane] = o;
}

extern "C" void kernel_launch(void* const* d_in, const int* in_sizes, int n_in,
                              void* d_out, int out_size, void* d_ws, size_t ws_size,
                              hipStream_t stream) {
    const float* x     = (const float*)d_in[0];
    const int*   idx   = (const int*)  d_in[1];
    const float* ea    = (const float*)d_in[2];
    const float* gs    = (const float*)d_in[3];
    const float* Wneg  = (const float*)d_in[4];
    const float* bneg  = (const float*)d_in[5];
    const float* Wroot = (const float*)d_in[6];
    const float* broot = (const float*)d_in[7];
    float* out = (float*)d_out;

    // ws layout (bytes):
    //   Y      : [0, 51.2e6)            N*128 floats
    //   cnt    : +0.4e6
    //   off    : +0.4e6
    //   cursor : +0.4e6
    //   eids   : +6.4e6                 total ~58.8 MB
    char* w = (char*)d_ws;
    float* Y     = (float*)w;                     w += (size_t)N_NODES * 128 * 4;
    int*   cnt   = (int*)w;                       w += (size_t)N_NODES * 4;
    int*   off   = (int*)w;                       w += (size_t)N_NODES * 4;
    int*   cur   = (int*)w;                       w += (size_t)N_NODES * 4;
    int*   eids  = (int*)w;

    const int nb_nodes = (N_NODES + 255) / 256;
    const int nb_edges = (N_EDGES + 255) / 256;

    node_gemm<<<N_NODES / 16, 256, 0, stream>>>(x, gs, Wneg, bneg, Wroot, broot, Y, out);
    zero_counts<<<nb_nodes, 256, 0, stream>>>(cnt);
    histogram<<<nb_edges, 256, 0, stream>>>(idx, cnt);
    scan_counts<<<1, 1024, 0, stream>>>(cnt, off, cur);
    scatter_edges<<<nb_edges, 256, 0, stream>>>(idx, cur, eids);
    aggregate<<<(N_NODES + 3) / 4, 256, 0, stream>>>(idx, ea, Wneg, Y, off, cnt, eids, out);
}